// Round 2
// baseline (18551.768 us; speedup 1.0000x reference)
//
#include <hip/hip_runtime.h>
#include <stdint.h>

#define Bsz 64
#define Tsz 1024
#define NIc 128
#define NHc 512
#define DTc 0.1f
#define RWG 16   // recurrent workgroups (32 cols each)
#define FLG 16   // flag stride in ints (64B apart)

typedef __attribute__((ext_vector_type(8))) short short8;
typedef __attribute__((ext_vector_type(4))) float f32x4;

static __device__ __forceinline__ unsigned short f2bf(float f) {
  union { float f; uint32_t u; } v; v.f = f;
  return (unsigned short)((v.u + 0x7fffu + ((v.u >> 16) & 1u)) >> 16);
}
static __device__ __forceinline__ float bf2f(unsigned short h) {
  union { float f; uint32_t u; } v; v.u = ((uint32_t)h) << 16; return v.f;
}
static __device__ __forceinline__ float fast_tanh(float xx) {
  float a = __builtin_fabsf(xx);
  float e = __expf(-2.0f * a);
  float r = (1.0f - e) / (1.0f + e);
  return __builtin_copysignf(r, xx);
}

// ---------------- kernel 1: forcing = tanh(x @ x2h), 256 WGs ----------------
__global__ __launch_bounds__(256, 1)
void pirn_force(const float* __restrict__ x, const float* __restrict__ x2h,
                float* __restrict__ out)
{
  __shared__ __align__(16) char lds[34816];
  const int tid  = threadIdx.x;
  const int lane = tid & 63;
  const int wv   = tid >> 6;
  const int l15  = lane & 15;
  const int quad = lane >> 4;
  unsigned short* x2ht_hi = (unsigned short*)lds;             // [64][136]
  unsigned short* x2ht_lo = (unsigned short*)(lds + 17408);   // [64][136]
  const long R0 = (long)blockIdx.x * 256;                     // 256 rows per WG

  for (int pass = 0; pass < 8; ++pass) {
    const int c0 = pass * 64;
    __syncthreads();
    for (int i = tid; i < 64 * NIc; i += 256) {
      int c = i & 63; int k = i >> 6;
      float v = x2h[k * NHc + c0 + c];
      unsigned short hi = f2bf(v);
      x2ht_hi[c * 136 + k] = hi;
      x2ht_lo[c * 136 + k] = f2bf(v - bf2f(hi));
    }
    __syncthreads();
    for (int mt = wv * 4; mt < wv * 4 + 4; ++mt) {
      const float* xr = x + (R0 + mt * 16 + l15) * NIc;
      short8 ahi[4], alo[4];
#pragma unroll
      for (int kb = 0; kb < 4; ++kb) {
        int k0 = kb * 32 + quad * 8;
        f32x4 v0 = *(const f32x4*)(xr + k0);
        f32x4 v1 = *(const f32x4*)(xr + k0 + 4);
#pragma unroll
        for (int e = 0; e < 4; ++e) {
          unsigned short h0 = f2bf(v0[e]);
          ahi[kb][e] = (short)h0;
          alo[kb][e] = (short)f2bf(v0[e] - bf2f(h0));
          unsigned short h1 = f2bf(v1[e]);
          ahi[kb][e + 4] = (short)h1;
          alo[kb][e + 4] = (short)f2bf(v1[e] - bf2f(h1));
        }
      }
#pragma unroll
      for (int nt = 0; nt < 4; ++nt) {
        f32x4 acc0 = {0.f, 0.f, 0.f, 0.f};
        f32x4 acc1 = {0.f, 0.f, 0.f, 0.f};
#pragma unroll
        for (int kb = 0; kb < 4; ++kb) {
          int k0 = kb * 32 + quad * 8;
          short8 bhi = *(const short8*)(x2ht_hi + (nt * 16 + l15) * 136 + k0);
          short8 blo = *(const short8*)(x2ht_lo + (nt * 16 + l15) * 136 + k0);
          acc0 = __builtin_amdgcn_mfma_f32_16x16x32_bf16(ahi[kb], bhi, acc0, 0, 0, 0);
          acc1 = __builtin_amdgcn_mfma_f32_16x16x32_bf16(alo[kb], bhi, acc1, 0, 0, 0);
          acc0 = __builtin_amdgcn_mfma_f32_16x16x32_bf16(ahi[kb], blo, acc0, 0, 0, 0);
        }
        long orow = R0 + mt * 16 + quad * 4;
        int oc = c0 + nt * 16 + l15;
#pragma unroll
        for (int r = 0; r < 4; ++r)
          out[(orow + r) * NHc + oc] = fast_tanh(acc0[r] + acc1[r]);
      }
    }
  }
}

// ---------------- sync helpers: per-access coherent, NO fences ----------------
static __device__ __forceinline__ void wait_flags(int* flags, int target, int tid) {
  if (tid < RWG) {
    while (__hip_atomic_load(&flags[tid * FLG], __ATOMIC_RELAXED,
                             __HIP_MEMORY_SCOPE_AGENT) < target)
      __builtin_amdgcn_s_sleep(1);
  }
  __syncthreads();
  __asm__ volatile("" ::: "memory");
}
static __device__ __forceinline__ void publish_flag(int* flags, int g, int val, int tid) {
  __asm__ volatile("" ::: "memory");
  __builtin_amdgcn_s_waitcnt(0);   // drain this wave's data stores (write-through, acked at device scope)
  __syncthreads();                 // all waves drained
  if (tid == 0)
    __hip_atomic_store(&flags[g * FLG], val, __ATOMIC_RELAXED,
                       __HIP_MEMORY_SCOPE_AGENT);
}

// ---------------- kernel 2: recurrent scan, 16 WGs x 32 cols ----------------
__global__ __launch_bounds__(256, 1)
void pirn_recur(const float* __restrict__ h2h, const float* __restrict__ bias,
                const float* __restrict__ gam_p, const float* __restrict__ eps_p,
                float* __restrict__ out, char* __restrict__ ws)
{
  const int g    = blockIdx.x;
  const int tid  = threadIdx.x;
  const int lane = tid & 63;
  const int wv   = tid >> 6;
  const int l15  = lane & 15;
  const int quad = lane >> 4;
  const int J0   = g * 32;

  int* hyflag  = (int*)ws;
  int* preflag = (int*)(ws + 2048);
  unsigned short* hybuf  = (unsigned short*)(ws + 8192);            // [2][64][512] bf16
  unsigned short* prebuf = (unsigned short*)(ws + 8192 + 131072);   // [2][64][512] bf16

  // ---- preload B-fragments into registers (constant over t) ----
  // phase1: pre = hy @ h2h      → B1[n][k] = h2h[k][J0+n]
  // phase2: c2  = pre @ h2h^T   → B2[n][k] = h2h[J0+n][k]
  short8 b1[2][16], b2[2][16];
#pragma unroll
  for (int nt = 0; nt < 2; ++nt) {
    const int col = J0 + nt * 16 + l15;
#pragma unroll 2
    for (int kb = 0; kb < 16; ++kb) {
      const int k0 = kb * 32 + quad * 8;
      short8 v1, v2;
#pragma unroll
      for (int e = 0; e < 8; ++e)
        v1[e] = (short)f2bf(h2h[(size_t)(k0 + e) * NHc + col]);
      f32x4 w0 = *(const f32x4*)(h2h + (size_t)col * NHc + k0);
      f32x4 w1 = *(const f32x4*)(h2h + (size_t)col * NHc + k0 + 4);
#pragma unroll
      for (int e = 0; e < 4; ++e) {
        v2[e]     = (short)f2bf(w0[e]);
        v2[e + 4] = (short)f2bf(w1[e]);
      }
      b1[nt][kb] = v1;
      b2[nt][kb] = v2;
    }
  }

  float b_c[2], gm[2], ep[2];
#pragma unroll
  for (int nt = 0; nt < 2; ++nt) {
    const int col = J0 + nt * 16 + l15;
    b_c[nt] = bias[col];
    gm[nt]  = gam_p[col];
    ep[nt]  = eps_p[col];
  }

  const int arow = wv * 16 + l15;       // A-frag row
  const int crow = wv * 16 + quad * 4;  // C/D base row
  float hy_r[2][4] = {{0.f,0.f,0.f,0.f},{0.f,0.f,0.f,0.f}};
  float hz_r[2][4] = {{0.f,0.f,0.f,0.f},{0.f,0.f,0.f,0.f}};

  for (int t = 0; t < Tsz; ++t) {
    // forcing prefetch (plain cached loads; written by pirn_force, own slots only)
    float u_r[2][4];
#pragma unroll
    for (int nt = 0; nt < 2; ++nt)
#pragma unroll
      for (int r = 0; r < 4; ++r)
        u_r[nt][r] = out[((size_t)(crow + r) * Tsz + t) * NHc + J0 + nt * 16 + l15];

    // ---- phase 1: pre = tanh(hy @ h2h + bias), own 32 cols ----
    f32x4 p1a[2] = {{0.f,0.f,0.f,0.f},{0.f,0.f,0.f,0.f}};
    f32x4 p1b[2] = {{0.f,0.f,0.f,0.f},{0.f,0.f,0.f,0.f}};
    if (t > 0) {
      wait_flags(hyflag, t, tid);
      unsigned long long* hb64 =
          (unsigned long long*)(hybuf + (size_t)(t & 1) * (Bsz * NHc) + (size_t)arow * NHc);
      unsigned long long w0[16], w1[16];
#pragma unroll
      for (int kb = 0; kb < 16; ++kb) {
        const int bi = kb * 8 + quad * 2;
        w0[kb] = __hip_atomic_load(hb64 + bi,     __ATOMIC_RELAXED, __HIP_MEMORY_SCOPE_AGENT);
        w1[kb] = __hip_atomic_load(hb64 + bi + 1, __ATOMIC_RELAXED, __HIP_MEMORY_SCOPE_AGENT);
      }
#pragma unroll
      for (int kb = 0; kb < 16; ++kb) {
        union { unsigned long long q[2]; short8 s; } uu;
        uu.q[0] = w0[kb]; uu.q[1] = w1[kb];
        if (kb & 1) {
          p1b[0] = __builtin_amdgcn_mfma_f32_16x16x32_bf16(uu.s, b1[0][kb], p1b[0], 0, 0, 0);
          p1b[1] = __builtin_amdgcn_mfma_f32_16x16x32_bf16(uu.s, b1[1][kb], p1b[1], 0, 0, 0);
        } else {
          p1a[0] = __builtin_amdgcn_mfma_f32_16x16x32_bf16(uu.s, b1[0][kb], p1a[0], 0, 0, 0);
          p1a[1] = __builtin_amdgcn_mfma_f32_16x16x32_bf16(uu.s, b1[1][kb], p1a[1], 0, 0, 0);
        }
      }
    }
    float pre[2][4];
#pragma unroll
    for (int nt = 0; nt < 2; ++nt)
#pragma unroll
      for (int r = 0; r < 4; ++r)
        pre[nt][r] = fast_tanh(p1a[nt][r] + p1b[nt][r] + b_c[nt]);

    // publish pre slice (per-access coherent bf16 stores)
    {
      unsigned short* pb = prebuf + (size_t)(t & 1) * (Bsz * NHc);
#pragma unroll
      for (int nt = 0; nt < 2; ++nt)
#pragma unroll
        for (int r = 0; r < 4; ++r)
          __hip_atomic_store(pb + (size_t)(crow + r) * NHc + J0 + nt * 16 + l15,
                             (unsigned short)f2bf(pre[nt][r]),
                             __ATOMIC_RELAXED, __HIP_MEMORY_SCOPE_AGENT);
    }
    publish_flag(preflag, g, t + 1, tid);
    wait_flags(preflag, t + 1, tid);

    // ---- phase 2: c2 = pre @ h2h^T, own 32 cols ----
    f32x4 p2a[2] = {{0.f,0.f,0.f,0.f},{0.f,0.f,0.f,0.f}};
    f32x4 p2b[2] = {{0.f,0.f,0.f,0.f},{0.f,0.f,0.f,0.f}};
    {
      unsigned long long* pb64 =
          (unsigned long long*)(prebuf + (size_t)(t & 1) * (Bsz * NHc) + (size_t)arow * NHc);
      unsigned long long w0[16], w1[16];
#pragma unroll
      for (int kb = 0; kb < 16; ++kb) {
        const int bi = kb * 8 + quad * 2;
        w0[kb] = __hip_atomic_load(pb64 + bi,     __ATOMIC_RELAXED, __HIP_MEMORY_SCOPE_AGENT);
        w1[kb] = __hip_atomic_load(pb64 + bi + 1, __ATOMIC_RELAXED, __HIP_MEMORY_SCOPE_AGENT);
      }
#pragma unroll
      for (int kb = 0; kb < 16; ++kb) {
        union { unsigned long long q[2]; short8 s; } uu;
        uu.q[0] = w0[kb]; uu.q[1] = w1[kb];
        if (kb & 1) {
          p2b[0] = __builtin_amdgcn_mfma_f32_16x16x32_bf16(uu.s, b2[0][kb], p2b[0], 0, 0, 0);
          p2b[1] = __builtin_amdgcn_mfma_f32_16x16x32_bf16(uu.s, b2[1][kb], p2b[1], 0, 0, 0);
        } else {
          p2a[0] = __builtin_amdgcn_mfma_f32_16x16x32_bf16(uu.s, b2[0][kb], p2a[0], 0, 0, 0);
          p2a[1] = __builtin_amdgcn_mfma_f32_16x16x32_bf16(uu.s, b2[1][kb], p2a[1], 0, 0, 0);
        }
      }
    }

    // ---- state update + output ----
#pragma unroll
    for (int nt = 0; nt < 2; ++nt) {
#pragma unroll
      for (int r = 0; r < 4; ++r) {
        float c2 = p2a[nt][r] + p2b[nt][r];
        float hz = hz_r[nt][r] + DTc * (u_r[nt][r] - c2 - gm[nt] * hy_r[nt][r] - ep[nt] * hz_r[nt][r]);
        hz_r[nt][r] = hz;
        hy_r[nt][r] += DTc * hz;
        out[((size_t)(crow + r) * Tsz + t) * NHc + J0 + nt * 16 + l15] = hy_r[nt][r];
      }
    }

    if (t + 1 < Tsz) {
      unsigned short* hbw = hybuf + (size_t)((t + 1) & 1) * (Bsz * NHc);
#pragma unroll
      for (int nt = 0; nt < 2; ++nt)
#pragma unroll
        for (int r = 0; r < 4; ++r)
          __hip_atomic_store(hbw + (size_t)(crow + r) * NHc + J0 + nt * 16 + l15,
                             (unsigned short)f2bf(hy_r[nt][r]),
                             __ATOMIC_RELAXED, __HIP_MEMORY_SCOPE_AGENT);
      publish_flag(hyflag, g, t + 1, tid);
    } else {
#pragma unroll
      for (int nt = 0; nt < 2; ++nt)
#pragma unroll
        for (int r = 0; r < 4; ++r)
          out[(size_t)Bsz * Tsz * NHc + (size_t)(crow + r) * NHc + J0 + nt * 16 + l15] = hy_r[nt][r];
    }
  }
}

extern "C" void kernel_launch(void* const* d_in, const int* in_sizes, int n_in,
                              void* d_out, int out_size, void* d_ws, size_t ws_size,
                              hipStream_t stream) {
  const float* x    = (const float*)d_in[0];
  const float* x2h  = (const float*)d_in[1];
  const float* h2h  = (const float*)d_in[2];
  const float* bias = (const float*)d_in[3];
  const float* gam  = (const float*)d_in[4];
  const float* eps  = (const float*)d_in[5];
  (void)in_sizes; (void)n_in; (void)out_size; (void)ws_size;
  pirn_force<<<dim3(256), dim3(256), 0, stream>>>(x, x2h, (float*)d_out);
  pirn_recur<<<dim3(RWG), dim3(256), 0, stream>>>(h2h, bias, gam, eps,
                                                  (float*)d_out, (char*)d_ws);
}